// Round 11
// baseline (669.426 us; speedup 1.0000x reference)
//
#include <hip/hip_runtime.h>

// ---------------------------------------------------------------------------
// FastRCNN head: RoIPool + FC(25088->4096) + FC(4096->4096) + heads (21/84).
// R11: barrier-free LDS-free GEMM. Finding from R7-R10: VGPR cap =
// 1024/waves_per_block (allocator budgets 2 resident blocks) -> only 4-wave
// (256-thr) blocks get 256 VGPRs. Each wave owns an independent 128x64 tile:
// acc[8][4]=128 + af 32 + B-raw 2x32 = ~245 regs, no spill. No LDS, no
// s_barrier, no lgkmcnt -> the ~2000cy/iter lockstep overhead of R4-R10 gone.
// B frags loaded per-wave straight from global (L2/HBM), cvt at consume.
// ---------------------------------------------------------------------------

typedef __attribute__((ext_vector_type(8))) __bf16 bf16x8;
typedef __attribute__((ext_vector_type(4))) float f32x4;

#define N_ROIS 512
#define FH 50
#define FW 50
#define KK1 25088      // 512*49
#define D1 4096
#define BK 32

// ---------------------------------------------------------------------------
// RoIPool: block = (roi, channel-group of 64). 4096 blocks (validated R5-R10).
// ---------------------------------------------------------------------------
__global__ __launch_bounds__(256) void roipool_kernel(
    const float* __restrict__ x, const float* __restrict__ rois,
    __bf16* __restrict__ pooled) {
  const int bid = blockIdx.x;
  const int roi = bid >> 3;
  const int cg = bid & 7;
  const float s = 0.0625f;
  const float r0 = rois[roi * 4 + 0], r1 = rois[roi * 4 + 1];
  const float r2 = rois[roi * 4 + 2], r3 = rois[roi * 4 + 3];
  int x1 = (int)(r0 * s); x1 = min(max(x1, 0), FW - 1);
  int y1 = (int)(r1 * s); y1 = min(max(y1, 0), FH - 1);
  int x2 = (int)(r2 * s); x2 = min(max(x2, 0), FW - 1);
  int y2 = (int)(r3 * s); y2 = min(max(y2, 0), FH - 1);
  const int ww = x2 - x1 + 1, hh = y2 - y1 + 1;
  __shared__ int cs[7], ce[7], rs[7], re[7];
  if (threadIdx.x < 7) {
    int i = threadIdx.x;
    cs[i] = x1 + (i * ww) / 7;
    ce[i] = x1 + ((i + 1) * ww + 6) / 7;
    rs[i] = y1 + (i * hh) / 7;
    re[i] = y1 + ((i + 1) * hh + 6) / 7;
  }
  __syncthreads();
  for (int idx = threadIdx.x; idx < 64 * 49; idx += 256) {
    int cl = idx / 49;
    int p = idx - cl * 49;
    int py = p / 7, px = p - py * 7;
    const int c = cg * 64 + cl;
    const float* base = x + (size_t)c * (FH * FW);
    float m = -3.402823466e38f;
    for (int y = rs[py]; y < re[py]; ++y) {
      const float* rowp = base + y * FW;
      for (int xx = cs[px]; xx < ce[px]; ++xx) m = fmaxf(m, rowp[xx]);
    }
    pooled[(size_t)roi * KK1 + c * 49 + p] = (__bf16)m;
  }
}

// ---------------------------------------------------------------------------
// GEMM: part[z][512][npad] = A[512,K](bf16) @ B[K,N](fp32 -> bf16 at consume)
// Grid: 256-thread blocks = 4 independent waves. Wave tile 128 rows x 64 cols.
// bid: z = bid & zmask (XCD-pins K-window), n-tile = bid >> zshift.
// Wave w owns rows w*128..w*128+127. No LDS, no barriers.
// Per iter: 8x A dwordx4 (L2-hot via z-pin); 32x B dword (HBM stream, raw f32
// kept 2 iters deep in regs, cvt to bf16 at consume); 32 MFMA 16x16x32.
// acc[8][4]=128 + af 32 + 2x32 raw B 64 + misc ~= 245 VGPR (cap 256, no spill).
// ---------------------------------------------------------------------------
template <typename OutT>
__global__ __launch_bounds__(256, 2) void gemm_kernel(
    const __bf16* __restrict__ A, const float* __restrict__ B,
    OutT* __restrict__ part, int N, int K, int kslice, int npad, int zshift) {
  const int tid = threadIdx.x;
  const int lane = tid & 63;
  const int w = tid >> 6;
  const int bid = blockIdx.x;
  const int z = bid & ((1 << zshift) - 1);
  const int n0 = (bid >> zshift) * 64;
  const int kbeg = z * kslice;
  const int niters = kslice / BK;  // 98, 16, or 2 -> always even
  const int kmax = kbeg + kslice;
  const int fr = lane & 15;
  const int ks = lane >> 4;
  const int m0 = w * 128;
  const bool fullN = (n0 + 64) <= N;

  f32x4 acc[8][4];
#pragma unroll
  for (int i = 0; i < 8; ++i)
#pragma unroll
    for (int j = 0; j < 4; ++j) acc[i][j] = (f32x4){0.f, 0.f, 0.f, 0.f};

  // A: lane reads rows m0 + mf*16 + fr, 16B at k = kbeg + it*32 + ks*8
  const __bf16* Abase = A + (size_t)(m0 + fr) * K + kbeg + ks * 8;
  const size_t Astride = (size_t)16 * K;  // bf16 elems between mf rows

  // B: lane (ks,fr) needs B[kg + ks*8 + e][n0 + nf*16 + fr], e=0..7, nf=0..3
  const float* Bbase = B + n0 + fr;

  bf16x8 af[8];        // constant-indexed (fully unrolled) -> registers
  float bA[32], bB[32];  // raw f32, [e*4 + nf], 2 slots

#define LOAD_B(S, t)                                                     \
  {                                                                      \
    int kg = kbeg + (t) * BK;                                            \
    if (kg >= kmax) kg = kbeg; /* clamped dup, never consumed */         \
    const float* p = Bbase + (size_t)(kg + ks * 8) * N;                  \
    if (fullN) {                                                         \
      _Pragma("unroll") for (int e = 0; e < 8; ++e) {                    \
        _Pragma("unroll") for (int nf = 0; nf < 4; ++nf)                 \
            S[e * 4 + nf] = p[nf * 16];                                  \
        p += N;                                                          \
      }                                                                  \
    } else {                                                             \
      _Pragma("unroll") for (int e = 0; e < 8; ++e) {                    \
        _Pragma("unroll") for (int nf = 0; nf < 4; ++nf)                 \
            S[e * 4 + nf] =                                              \
                (n0 + nf * 16 + fr < N) ? p[nf * 16] : 0.f;              \
        p += N;                                                          \
      }                                                                  \
    }                                                                    \
  }

#define BODY(it, CUR)                                                    \
  {                                                                      \
    const __bf16* ap = Abase + (size_t)(it) * BK;                        \
    _Pragma("unroll") for (int i = 0; i < 8; ++i)                        \
        af[i] = *(const bf16x8*)(ap + (size_t)i * Astride);              \
    bf16x8 bfr[4];                                                       \
    _Pragma("unroll") for (int e = 0; e < 8; ++e)                        \
        _Pragma("unroll") for (int nf = 0; nf < 4; ++nf)                 \
            bfr[nf][e] = (__bf16)CUR[e * 4 + nf];                        \
    LOAD_B(CUR, (it) + 2);                                               \
    _Pragma("unroll") for (int nf = 0; nf < 4; ++nf)                     \
        _Pragma("unroll") for (int mf = 0; mf < 8; ++mf)                 \
            acc[mf][nf] = __builtin_amdgcn_mfma_f32_16x16x32_bf16(       \
                af[mf], bfr[nf], acc[mf][nf], 0, 0, 0);                  \
  }

  // prologue: B tiles 0,1 in flight
  LOAD_B(bA, 0);
  LOAD_B(bB, 1);

  for (int it = 0; it < niters; it += 2) {
    BODY(it, bA);
    BODY(it + 1, bB);
  }
#undef BODY
#undef LOAD_B

  // epilogue: C/D layout col = lane&15, row = (lane>>4)*4 + r
  const int r0 = ks * 4;
  OutT* pbase = part + (size_t)z * 512 * npad;
#pragma unroll
  for (int mf = 0; mf < 8; ++mf)
#pragma unroll
    for (int nf = 0; nf < 4; ++nf) {
      const int col = n0 + nf * 16 + fr;
#pragma unroll
      for (int r = 0; r < 4; ++r) {
        const int row = m0 + mf * 16 + r0 + r;
        pbase[(size_t)row * npad + col] = (OutT)acc[mf][nf][r];
      }
    }
}

// sum bf16 split-K partials + bias, relu -> bf16 activations [512][4096]
__global__ __launch_bounds__(256) void reduce_relu_kernel(
    const __bf16* __restrict__ part, const float* __restrict__ bias,
    __bf16* __restrict__ out, int nsplit) {
  const int idx = blockIdx.x * 256 + threadIdx.x;
  const int flat = idx * 8;
  if (flat >= 512 * 4096) return;
  float s[8];
#pragma unroll
  for (int j = 0; j < 8; ++j) s[j] = 0.f;
  for (int sp = 0; sp < nsplit; ++sp) {
    bf16x8 v = *(const bf16x8*)(part + (size_t)sp * (512 * 4096) + flat);
#pragma unroll
    for (int j = 0; j < 8; ++j) s[j] += (float)v[j];
  }
  const int nb = flat & 4095;
  bf16x8 o;
#pragma unroll
  for (int j = 0; j < 8; ++j) {
    float v = s[j] + bias[nb + j];
    o[j] = (__bf16)(v > 0.f ? v : 0.f);
  }
  *(bf16x8*)(out + flat) = o;
}

// final: sum split-K fp32 partials (stride 128) + bias -> d_out fp32
__global__ __launch_bounds__(256) void reduce_out_kernel(
    const float* __restrict__ pc, const float* __restrict__ pr,
    const float* __restrict__ bcls, const float* __restrict__ breg,
    float* __restrict__ out, int nsplit) {
  const int gid = blockIdx.x * 256 + threadIdx.x;
  if (gid >= 512 * 105) return;
  if (gid < 512 * 21) {
    const int m = gid / 21, j = gid - m * 21;
    float s = bcls[j];
    for (int sp = 0; sp < nsplit; ++sp)
      s += pc[(size_t)sp * 512 * 128 + m * 128 + j];
    out[gid] = s;
  } else {
    const int g = gid - 512 * 21;
    const int m = g / 84, j = g - m * 84;
    float s = breg[j];
    for (int sp = 0; sp < nsplit; ++sp)
      s += pr[(size_t)sp * 512 * 128 + m * 128 + j];
    out[gid] = s;
  }
}

extern "C" void kernel_launch(void* const* d_in, const int* in_sizes, int n_in,
                              void* d_out, int out_size, void* d_ws, size_t ws_size,
                              hipStream_t stream) {
  (void)in_sizes; (void)n_in; (void)out_size;
  const float* x    = (const float*)d_in[0];
  const float* rois = (const float*)d_in[2];
  const float* W1   = (const float*)d_in[3];
  const float* b1   = (const float*)d_in[4];
  const float* W2   = (const float*)d_in[5];
  const float* b2   = (const float*)d_in[6];
  const float* Wcls = (const float*)d_in[7];
  const float* bcls = (const float*)d_in[8];
  const float* Wreg = (const float*)d_in[9];
  const float* breg = (const float*)d_in[10];
  float* out = (float*)d_out;

  const size_t pooled_b = (size_t)512 * KK1 * 2;        // 25,690,112
  const size_t act_b = (size_t)512 * D1 * 2;            // 4 MiB
  const size_t need8 = pooled_b + (size_t)8 * act_b + 2 * act_b;
  const int ns = (ws_size >= need8) ? 8 : 2;            // ws ~1.6GB: ns=8
  const int zshift = (ns == 8) ? 3 : 1;

  char* ws = (char*)d_ws;
  __bf16* pooled = (__bf16*)ws;
  __bf16* part1 = (__bf16*)(ws + pooled_b);             // ns * 4MiB
  __bf16* f1 = (__bf16*)(ws + pooled_b + (size_t)ns * act_b);
  __bf16* f2 = (__bf16*)(ws + pooled_b + (size_t)ns * act_b + act_b);
  __bf16* part2 = (__bf16*)ws;                          // alias dead pooled+part1
  float* pcls = (float*)ws;                             // heads phase aliases
  float* preg = (float*)(ws + (size_t)64 * 512 * 128 * 4);  // +16.8MB

  // 1) RoIPool -> pooled bf16 [512, 25088]; 4096 blocks for occupancy
  roipool_kernel<<<N_ROIS * 8, 256, 0, stream>>>(x, rois, pooled);

  // 2) GEMM1: pooled @ W1[25088,4096]; W1 read exactly once; z-pinned XCDs
  gemm_kernel<__bf16><<<64 * ns, 256, 0, stream>>>(
      pooled, W1, part1, 4096, KK1, KK1 / ns, 4096, zshift);
  reduce_relu_kernel<<<1024, 256, 0, stream>>>(part1, b1, f1, ns);

  // 3) GEMM2: f1 @ W2[4096,4096]
  gemm_kernel<__bf16><<<64 * ns, 256, 0, stream>>>(
      f1, W2, part2, 4096, 4096, 4096 / ns, 4096, zshift);
  reduce_relu_kernel<<<1024, 256, 0, stream>>>(part2, b2, f2, ns);

  // 4) heads: single 64-col tile (21,84: Wreg needs 2 tiles), split-K=64
  gemm_kernel<float><<<64, 256, 0, stream>>>(
      f2, Wcls, pcls, 21, 4096, 64, 128, 6);
  gemm_kernel<float><<<128, 256, 0, stream>>>(
      f2, Wreg, preg, 84, 4096, 64, 128, 6);
  reduce_out_kernel<<<(512 * 105 + 255) / 256, 256, 0, stream>>>(
      pcls, preg, bcls, breg, out, 64);
}

// Round 12
// 484.785 us; speedup vs baseline: 1.3809x; 1.3809x over previous
//
#include <hip/hip_runtime.h>

// ---------------------------------------------------------------------------
// FastRCNN head: RoIPool + FC(25088->4096) + FC(4096->4096) + heads (21/84).
// R12 = R11 (barrier-free, LDS-free, per-wave 128x64 tiles) with the register
// budget actually granted: __launch_bounds__(256, 1) -> 1 wave/SIMD -> up to
// 512 regs/wave (arch + acc). R11's (256,2) forced 2 waves/SIMD -> 128 arch
// VGPRs -> ~40-reg spill (WRITE_SIZE 589MB). Also adds A 1-deep ping-pong
// (now affordable) so both A and B latencies are covered in-wave.
// ---------------------------------------------------------------------------

typedef __attribute__((ext_vector_type(8))) __bf16 bf16x8;
typedef __attribute__((ext_vector_type(4))) float f32x4;

#define N_ROIS 512
#define FH 50
#define FW 50
#define KK1 25088      // 512*49
#define D1 4096
#define BK 32

// ---------------------------------------------------------------------------
// RoIPool: block = (roi, channel-group of 64). 4096 blocks (validated R5-R11).
// ---------------------------------------------------------------------------
__global__ __launch_bounds__(256) void roipool_kernel(
    const float* __restrict__ x, const float* __restrict__ rois,
    __bf16* __restrict__ pooled) {
  const int bid = blockIdx.x;
  const int roi = bid >> 3;
  const int cg = bid & 7;
  const float s = 0.0625f;
  const float r0 = rois[roi * 4 + 0], r1 = rois[roi * 4 + 1];
  const float r2 = rois[roi * 4 + 2], r3 = rois[roi * 4 + 3];
  int x1 = (int)(r0 * s); x1 = min(max(x1, 0), FW - 1);
  int y1 = (int)(r1 * s); y1 = min(max(y1, 0), FH - 1);
  int x2 = (int)(r2 * s); x2 = min(max(x2, 0), FW - 1);
  int y2 = (int)(r3 * s); y2 = min(max(y2, 0), FH - 1);
  const int ww = x2 - x1 + 1, hh = y2 - y1 + 1;
  __shared__ int cs[7], ce[7], rs[7], re[7];
  if (threadIdx.x < 7) {
    int i = threadIdx.x;
    cs[i] = x1 + (i * ww) / 7;
    ce[i] = x1 + ((i + 1) * ww + 6) / 7;
    rs[i] = y1 + (i * hh) / 7;
    re[i] = y1 + ((i + 1) * hh + 6) / 7;
  }
  __syncthreads();
  for (int idx = threadIdx.x; idx < 64 * 49; idx += 256) {
    int cl = idx / 49;
    int p = idx - cl * 49;
    int py = p / 7, px = p - py * 7;
    const int c = cg * 64 + cl;
    const float* base = x + (size_t)c * (FH * FW);
    float m = -3.402823466e38f;
    for (int y = rs[py]; y < re[py]; ++y) {
      const float* rowp = base + y * FW;
      for (int xx = cs[px]; xx < ce[px]; ++xx) m = fmaxf(m, rowp[xx]);
    }
    pooled[(size_t)roi * KK1 + c * 49 + p] = (__bf16)m;
  }
}

// ---------------------------------------------------------------------------
// GEMM: part[z][512][npad] = A[512,K](bf16) @ B[K,N](fp32 -> bf16 at consume)
// 256-thr blocks = 4 independent waves, 1 wave/SIMD (launch_bounds(256,1)).
// Wave tile 128 rows x 64 cols; z = bid & zmask (XCD-pin), ntile = bid>>zshift.
// Per iter: 8 A dwordx4 (L2-hot, 1-deep ping-pong), 32 B dword (HBM stream,
// raw f32 2-deep), cvt->bf16 at consume, 32 MFMA. No LDS, no barriers.
// Regs: acc 128 (AGPR) + afA/afB 64 + bA/bB 64 + transient ~40 -> fits 512.
// ---------------------------------------------------------------------------
template <typename OutT>
__global__ __launch_bounds__(256, 1) void gemm_kernel(
    const __bf16* __restrict__ A, const float* __restrict__ B,
    OutT* __restrict__ part, int N, int K, int kslice, int npad, int zshift) {
  const int tid = threadIdx.x;
  const int lane = tid & 63;
  const int w = tid >> 6;
  const int bid = blockIdx.x;
  const int z = bid & ((1 << zshift) - 1);
  const int n0 = (bid >> zshift) * 64;
  const int kbeg = z * kslice;
  const int niters = kslice / BK;  // 98, 16, or 2 -> always even
  const int kmax = kbeg + kslice;
  const int fr = lane & 15;
  const int ks = lane >> 4;
  const int m0 = w * 128;
  const bool fullN = (n0 + 64) <= N;

  f32x4 acc[8][4];
#pragma unroll
  for (int i = 0; i < 8; ++i)
#pragma unroll
    for (int j = 0; j < 4; ++j) acc[i][j] = (f32x4){0.f, 0.f, 0.f, 0.f};

  // A: lane reads rows m0 + mf*16 + fr, 16B at k = kbeg + it*32 + ks*8
  const __bf16* Abase = A + (size_t)(m0 + fr) * K + ks * 8;
  const size_t Astride = (size_t)16 * K;  // bf16 elems between mf rows

  // B: lane (ks,fr) needs B[kg + ks*8 + e][n0 + nf*16 + fr], e=0..7, nf=0..3
  const float* Bbase = B + n0 + fr;

  bf16x8 afA[8], afB[8];   // A frags, 1-deep ping-pong (const-indexed only)
  float bA[32], bB[32];    // raw f32 B, [e*4 + nf], 2-deep

#define LOAD_A(D, t)                                                     \
  {                                                                      \
    int kk = kbeg + (t) * BK;                                            \
    if (kk >= kmax) kk = kbeg; /* clamped dup, never consumed */         \
    const __bf16* ap = Abase + kk;                                       \
    _Pragma("unroll") for (int i = 0; i < 8; ++i)                        \
        D[i] = *(const bf16x8*)(ap + (size_t)i * Astride);               \
  }

#define LOAD_B(S, t)                                                     \
  {                                                                      \
    int kg = kbeg + (t) * BK;                                            \
    if (kg >= kmax) kg = kbeg; /* clamped dup, never consumed */         \
    const float* p = Bbase + (size_t)(kg + ks * 8) * N;                  \
    if (fullN) {                                                         \
      _Pragma("unroll") for (int e = 0; e < 8; ++e) {                    \
        _Pragma("unroll") for (int nf = 0; nf < 4; ++nf)                 \
            S[e * 4 + nf] = p[nf * 16];                                  \
        p += N;                                                          \
      }                                                                  \
    } else {                                                             \
      _Pragma("unroll") for (int e = 0; e < 8; ++e) {                    \
        _Pragma("unroll") for (int nf = 0; nf < 4; ++nf)                 \
            S[e * 4 + nf] =                                              \
                (n0 + nf * 16 + fr < N) ? p[nf * 16] : 0.f;              \
        p += N;                                                          \
      }                                                                  \
    }                                                                    \
  }

  // BODY(it): cvt curB (arrived: issued it-2) -> bfr; refill curB with
  // tile it+2; load A tile it+1 into the alternate slot; MFMA with curA
  // (issued at it-1 -> ~1 iter of slack).
#define BODY(it, CA, NA, CB)                                             \
  {                                                                      \
    bf16x8 bfr[4];                                                       \
    _Pragma("unroll") for (int e = 0; e < 8; ++e)                        \
        _Pragma("unroll") for (int nf = 0; nf < 4; ++nf)                 \
            bfr[nf][e] = (__bf16)CB[e * 4 + nf];                         \
    LOAD_B(CB, (it) + 2);                                                \
    LOAD_A(NA, (it) + 1);                                                \
    _Pragma("unroll") for (int nf = 0; nf < 4; ++nf)                     \
        _Pragma("unroll") for (int mf = 0; mf < 8; ++mf)                 \
            acc[mf][nf] = __builtin_amdgcn_mfma_f32_16x16x32_bf16(       \
                CA[mf], bfr[nf], acc[mf][nf], 0, 0, 0);                  \
  }

  // prologue: A tile 0; B tiles 0,1 in flight
  LOAD_A(afA, 0);
  LOAD_B(bA, 0);
  LOAD_B(bB, 1);

  for (int it = 0; it < niters; it += 2) {
    BODY(it, afA, afB, bA);
    BODY(it + 1, afB, afA, bB);
  }
#undef BODY
#undef LOAD_B
#undef LOAD_A

  // epilogue: C/D layout col = lane&15, row = (lane>>4)*4 + r
  const int r0 = ks * 4;
  OutT* pbase = part + (size_t)z * 512 * npad;
#pragma unroll
  for (int mf = 0; mf < 8; ++mf)
#pragma unroll
    for (int nf = 0; nf < 4; ++nf) {
      const int col = n0 + nf * 16 + fr;
#pragma unroll
      for (int r = 0; r < 4; ++r) {
        const int row = m0 + mf * 16 + r0 + r;
        pbase[(size_t)row * npad + col] = (OutT)acc[mf][nf][r];
      }
    }
}

// sum bf16 split-K partials + bias, relu -> bf16 activations [512][4096]
__global__ __launch_bounds__(256) void reduce_relu_kernel(
    const __bf16* __restrict__ part, const float* __restrict__ bias,
    __bf16* __restrict__ out, int nsplit) {
  const int idx = blockIdx.x * 256 + threadIdx.x;
  const int flat = idx * 8;
  if (flat >= 512 * 4096) return;
  float s[8];
#pragma unroll
  for (int j = 0; j < 8; ++j) s[j] = 0.f;
  for (int sp = 0; sp < nsplit; ++sp) {
    bf16x8 v = *(const bf16x8*)(part + (size_t)sp * (512 * 4096) + flat);
#pragma unroll
    for (int j = 0; j < 8; ++j) s[j] += (float)v[j];
  }
  const int nb = flat & 4095;
  bf16x8 o;
#pragma unroll
  for (int j = 0; j < 8; ++j) {
    float v = s[j] + bias[nb + j];
    o[j] = (__bf16)(v > 0.f ? v : 0.f);
  }
  *(bf16x8*)(out + flat) = o;
}

// final: sum split-K fp32 partials (stride 128) + bias -> d_out fp32
__global__ __launch_bounds__(256) void reduce_out_kernel(
    const float* __restrict__ pc, const float* __restrict__ pr,
    const float* __restrict__ bcls, const float* __restrict__ breg,
    float* __restrict__ out, int nsplit) {
  const int gid = blockIdx.x * 256 + threadIdx.x;
  if (gid >= 512 * 105) return;
  if (gid < 512 * 21) {
    const int m = gid / 21, j = gid - m * 21;
    float s = bcls[j];
    for (int sp = 0; sp < nsplit; ++sp)
      s += pc[(size_t)sp * 512 * 128 + m * 128 + j];
    out[gid] = s;
  } else {
    const int g = gid - 512 * 21;
    const int m = g / 84, j = g - m * 84;
    float s = breg[j];
    for (int sp = 0; sp < nsplit; ++sp)
      s += pr[(size_t)sp * 512 * 128 + m * 128 + j];
    out[gid] = s;
  }
}

extern "C" void kernel_launch(void* const* d_in, const int* in_sizes, int n_in,
                              void* d_out, int out_size, void* d_ws, size_t ws_size,
                              hipStream_t stream) {
  (void)in_sizes; (void)n_in; (void)out_size;
  const float* x    = (const float*)d_in[0];
  const float* rois = (const float*)d_in[2];
  const float* W1   = (const float*)d_in[3];
  const float* b1   = (const float*)d_in[4];
  const float* W2   = (const float*)d_in[5];
  const float* b2   = (const float*)d_in[6];
  const float* Wcls = (const float*)d_in[7];
  const float* bcls = (const float*)d_in[8];
  const float* Wreg = (const float*)d_in[9];
  const float* breg = (const float*)d_in[10];
  float* out = (float*)d_out;

  const size_t pooled_b = (size_t)512 * KK1 * 2;        // 25,690,112
  const size_t act_b = (size_t)512 * D1 * 2;            // 4 MiB
  const size_t need8 = pooled_b + (size_t)8 * act_b + 2 * act_b;
  const int ns = (ws_size >= need8) ? 8 : 2;            // ws ~1.6GB: ns=8
  const int zshift = (ns == 8) ? 3 : 1;

  char* ws = (char*)d_ws;
  __bf16* pooled = (__bf16*)ws;
  __bf16* part1 = (__bf16*)(ws + pooled_b);             // ns * 4MiB
  __bf16* f1 = (__bf16*)(ws + pooled_b + (size_t)ns * act_b);
  __bf16* f2 = (__bf16*)(ws + pooled_b + (size_t)ns * act_b + act_b);
  __bf16* part2 = (__bf16*)ws;                          // alias dead pooled+part1
  float* pcls = (float*)ws;                             // heads phase aliases
  float* preg = (float*)(ws + (size_t)64 * 512 * 128 * 4);  // +16.8MB

  // 1) RoIPool -> pooled bf16 [512, 25088]; 4096 blocks for occupancy
  roipool_kernel<<<N_ROIS * 8, 256, 0, stream>>>(x, rois, pooled);

  // 2) GEMM1: pooled @ W1[25088,4096]; W1 read exactly once; z-pinned XCDs
  gemm_kernel<__bf16><<<64 * ns, 256, 0, stream>>>(
      pooled, W1, part1, 4096, KK1, KK1 / ns, 4096, zshift);
  reduce_relu_kernel<<<1024, 256, 0, stream>>>(part1, b1, f1, ns);

  // 3) GEMM2: f1 @ W2[4096,4096]
  gemm_kernel<__bf16><<<64 * ns, 256, 0, stream>>>(
      f1, W2, part2, 4096, 4096, 4096 / ns, 4096, zshift);
  reduce_relu_kernel<<<1024, 256, 0, stream>>>(part2, b2, f2, ns);

  // 4) heads: 64-col tiles (Wcls 1 tile, Wreg 2 tiles), split-K=64
  gemm_kernel<float><<<64, 256, 0, stream>>>(
      f2, Wcls, pcls, 21, 4096, 64, 128, 6);
  gemm_kernel<float><<<128, 256, 0, stream>>>(
      f2, Wreg, preg, 84, 4096, 64, 128, 6);
  reduce_out_kernel<<<(512 * 105 + 255) / 256, 256, 0, stream>>>(
      pcls, preg, bcls, breg, out, 64);
}

// Round 13
// 350.554 us; speedup vs baseline: 1.9096x; 1.3829x over previous
//
#include <hip/hip_runtime.h>

// ---------------------------------------------------------------------------
// FastRCNN head: RoIPool + FC(25088->4096) + FC(4096->4096) + heads (21/84).
// R13: gemm_pipe for GEMM1/2 — BM=512 x BN=128 per block (1 block/CU, W1 read
// once), 4 waves x (128x128), B staged via global_load_lds dwordx4 (16 req/CU
// /iter vs ~512 scalar in R12 — request-rate was the 3944cy/iter wall), LDS
// 4-buffer + counted vmcnt(16) (never 0; exact steady drain = B(it)+A(it-1)),
// XOR-swizzled source + swizzled ds_read (2-way, free). A direct to regs.
// acc[8][8]=256 AGPR + ~130 arch < 512 at (256,1): no spill (R12-verified
// budget model). Heads use the R12 no-LDS kernel (safe N<128 bounds).
// ---------------------------------------------------------------------------

typedef __attribute__((ext_vector_type(8))) __bf16 bf16x8;
typedef __attribute__((ext_vector_type(4))) float f32x4;

#define N_ROIS 512
#define FH 50
#define FW 50
#define KK1 25088      // 512*49
#define D1 4096
#define BK 32

__device__ __forceinline__ void gll16(const void* g, void* l) {
  __builtin_amdgcn_global_load_lds(
      (const __attribute__((address_space(1))) void*)g,
      (__attribute__((address_space(3))) void*)l, 16, 0, 0);
}

// ---------------------------------------------------------------------------
// RoIPool: block = (roi, channel-group of 64). 4096 blocks (validated R5-R12).
// ---------------------------------------------------------------------------
__global__ __launch_bounds__(256) void roipool_kernel(
    const float* __restrict__ x, const float* __restrict__ rois,
    __bf16* __restrict__ pooled) {
  const int bid = blockIdx.x;
  const int roi = bid >> 3;
  const int cg = bid & 7;
  const float s = 0.0625f;
  const float r0 = rois[roi * 4 + 0], r1 = rois[roi * 4 + 1];
  const float r2 = rois[roi * 4 + 2], r3 = rois[roi * 4 + 3];
  int x1 = (int)(r0 * s); x1 = min(max(x1, 0), FW - 1);
  int y1 = (int)(r1 * s); y1 = min(max(y1, 0), FH - 1);
  int x2 = (int)(r2 * s); x2 = min(max(x2, 0), FW - 1);
  int y2 = (int)(r3 * s); y2 = min(max(y2, 0), FH - 1);
  const int ww = x2 - x1 + 1, hh = y2 - y1 + 1;
  __shared__ int cs[7], ce[7], rs[7], re[7];
  if (threadIdx.x < 7) {
    int i = threadIdx.x;
    cs[i] = x1 + (i * ww) / 7;
    ce[i] = x1 + ((i + 1) * ww + 6) / 7;
    rs[i] = y1 + (i * hh) / 7;
    re[i] = y1 + ((i + 1) * hh + 6) / 7;
  }
  __syncthreads();
  for (int idx = threadIdx.x; idx < 64 * 49; idx += 256) {
    int cl = idx / 49;
    int p = idx - cl * 49;
    int py = p / 7, px = p - py * 7;
    const int c = cg * 64 + cl;
    const float* base = x + (size_t)c * (FH * FW);
    float m = -3.402823466e38f;
    for (int y = rs[py]; y < re[py]; ++y) {
      const float* rowp = base + y * FW;
      for (int xx = cs[px]; xx < ce[px]; ++xx) m = fmaxf(m, rowp[xx]);
    }
    pooled[(size_t)roi * KK1 + c * 49 + p] = (__bf16)m;
  }
}

// ---------------------------------------------------------------------------
// gemm_pipe: part[z][512][npad] = A[512,K](bf16) @ B[K,N](fp32, N%128==0)
// 256 thr = 4 waves; wave w owns rows w*128..+127, all 128 cols of the tile.
// z = bid & zmask (XCD-pin), n0 = (bid>>zshift)*128. niters = kslice/32.
// B tile 32x128 f32 = 16KB: 16 gll16/iter (4/wave; wave w stages rows
//   w*8+2i+(l>>5), LDS slot l&31 holds col-group (l&31)^(2w) -- XOR swizzle
//   via pre-swizzled SOURCE, LDS dest linear [32][128] f32).
// Read: lane(ks,fr), col c: slot=(c>>2)^(2*ks) -> bank 2-way (free).
// Pipeline: stage B(it+2) -> buf[(it+2)&3]; vmcnt(16) (exact: drains B(it)
//   + A(it-1) in steady state); s_barrier; ds_read+cvt+MFMA on buf[it&3].
// A: 8 dwordx4 to regs at iter top (L2-hot via z-pin), consumed ~200cy later.
// ---------------------------------------------------------------------------
template <typename OutT>
__global__ __launch_bounds__(256, 1) void gemm_pipe(
    const __bf16* __restrict__ A, const float* __restrict__ B,
    OutT* __restrict__ part, int N, int K, int kslice, int npad, int zshift) {
  __shared__ float Blds[4][32 * 128];  // 64 KB
  const int tid = threadIdx.x;
  const int lane = tid & 63;
  const int w = tid >> 6;  // 0..3
  const int bid = blockIdx.x;
  const int z = bid & ((1 << zshift) - 1);
  const int n0 = (bid >> zshift) * 128;
  const int kbeg = z * kslice;
  const int niters = kslice / BK;
  const int kmax = kbeg + kslice;
  const int fr = lane & 15;
  const int ks = lane >> 4;

  f32x4 acc[8][8];
#pragma unroll
  for (int i = 0; i < 8; ++i)
#pragma unroll
    for (int j = 0; j < 8; ++j) acc[i][j] = (f32x4){0.f, 0.f, 0.f, 0.f};

  // A: lane reads rows w*128 + mf*16 + fr, 16B at k = kbeg + it*32 + ks*8
  const __bf16* Abase = A + (size_t)(w * 128 + fr) * K + kbeg + ks * 8;
  const size_t Astride = (size_t)16 * K;

  // B staging: wave w, instr i, lane l -> global row kg + w*8 + 2i + (l>>5),
  // col-group (l&31)^(2w); LDS dest base = &Blds[buf][(w*8+2i)*128].
  const int srow = w * 8 + (lane >> 5);           // + 2i at issue
  const float* Bsrc = B + n0 + (((lane & 31) ^ (2 * w)) << 2);

  bf16x8 af[8];  // constant-indexed only -> registers

#define STAGE(buf, t)                                                     \
  {                                                                       \
    int kg = kbeg + (t) * BK;                                             \
    if (kg >= kmax) kg = kbeg; /* dup tile; only read if t < niters */    \
    _Pragma("unroll") for (int i = 0; i < 4; ++i) {                       \
      gll16((const void*)(Bsrc + (size_t)(kg + srow + 2 * i) * N),        \
            (void*)&Blds[buf][(w * 8 + 2 * i) * 128]);                    \
    }                                                                     \
  }

  // prologue: B(0)->buf0, B(1)->buf1
  STAGE(0, 0);
  STAGE(1, 1);

  for (int it = 0; it < niters; ++it) {
    // A for this iter (consumed after barrier + first ds_read/cvt ~200cy)
    {
      const __bf16* ap = Abase + (size_t)it * BK;
#pragma unroll
      for (int i = 0; i < 8; ++i)
        af[i] = *(const bf16x8*)(ap + (size_t)i * Astride);
    }
    STAGE((it + 2) & 3, it + 2);
    // exact steady-state drain: leaves A(it)8 + B(it+2)4 + B(it+1)4 = 16
    asm volatile("s_waitcnt vmcnt(16)" ::: "memory");
    __builtin_amdgcn_s_barrier();
    __builtin_amdgcn_sched_barrier(0);

    const float* bl = &Blds[it & 3][0];
#pragma unroll
    for (int nf = 0; nf < 8; ++nf) {
      // col c = nf*16 + fr; slot = (c>>2) ^ (2*ks); elem idx in f32:
      // (ks*8+e)*128 + slot*4 + (fr&3)
      const int base =
          (ks * 8) * 128 + (((nf * 4 + (fr >> 2)) ^ (2 * ks)) << 2) + (fr & 3);
      bf16x8 bfr;
#pragma unroll
      for (int e = 0; e < 8; ++e) bfr[e] = (__bf16)bl[base + e * 128];
#pragma unroll
      for (int mf = 0; mf < 8; ++mf)
        acc[mf][nf] = __builtin_amdgcn_mfma_f32_16x16x32_bf16(
            af[mf], bfr, acc[mf][nf], 0, 0, 0);
    }
  }
#undef STAGE

  // epilogue: C/D layout col = lane&15, row = (lane>>4)*4 + r
  const int r0 = ks * 4;
  OutT* pbase = part + (size_t)z * 512 * npad;
#pragma unroll
  for (int mf = 0; mf < 8; ++mf)
#pragma unroll
    for (int nf = 0; nf < 8; ++nf) {
      const int col = n0 + nf * 16 + fr;
#pragma unroll
      for (int r = 0; r < 4; ++r) {
        const int row = w * 128 + mf * 16 + r0 + r;
        pbase[(size_t)row * npad + col] = (OutT)acc[mf][nf][r];
      }
    }
}

// ---------------------------------------------------------------------------
// gemm_small (R12, validated): barrier-free LDS-free, per-wave 128x64 tile.
// Used for the tiny head GEMMs (handles N < 64 via per-lane guards).
// ---------------------------------------------------------------------------
template <typename OutT>
__global__ __launch_bounds__(256, 1) void gemm_small(
    const __bf16* __restrict__ A, const float* __restrict__ B,
    OutT* __restrict__ part, int N, int K, int kslice, int npad, int zshift) {
  const int tid = threadIdx.x;
  const int lane = tid & 63;
  const int w = tid >> 6;
  const int bid = blockIdx.x;
  const int z = bid & ((1 << zshift) - 1);
  const int n0 = (bid >> zshift) * 64;
  const int kbeg = z * kslice;
  const int niters = kslice / BK;
  const int kmax = kbeg + kslice;
  const int fr = lane & 15;
  const int ks = lane >> 4;
  const int m0 = w * 128;
  const bool fullN = (n0 + 64) <= N;

  f32x4 acc[8][4];
#pragma unroll
  for (int i = 0; i < 8; ++i)
#pragma unroll
    for (int j = 0; j < 4; ++j) acc[i][j] = (f32x4){0.f, 0.f, 0.f, 0.f};

  const __bf16* Abase = A + (size_t)(m0 + fr) * K + ks * 8;
  const size_t Astride = (size_t)16 * K;
  const float* Bbase = B + n0 + fr;

  bf16x8 afA[8], afB[8];
  float bA[32], bB[32];

#define LOAD_A(D, t)                                                     \
  {                                                                      \
    int kk = kbeg + (t) * BK;                                            \
    if (kk >= kmax) kk = kbeg;                                           \
    const __bf16* ap = Abase + kk;                                       \
    _Pragma("unroll") for (int i = 0; i < 8; ++i)                        \
        D[i] = *(const bf16x8*)(ap + (size_t)i * Astride);               \
  }

#define LOAD_B(S, t)                                                     \
  {                                                                      \
    int kg = kbeg + (t) * BK;                                            \
    if (kg >= kmax) kg = kbeg;                                           \
    const float* p = Bbase + (size_t)(kg + ks * 8) * N;                  \
    if (fullN) {                                                         \
      _Pragma("unroll") for (int e = 0; e < 8; ++e) {                    \
        _Pragma("unroll") for (int nf = 0; nf < 4; ++nf)                 \
            S[e * 4 + nf] = p[nf * 16];                                  \
        p += N;                                                          \
      }                                                                  \
    } else {                                                             \
      _Pragma("unroll") for (int e = 0; e < 8; ++e) {                    \
        _Pragma("unroll") for (int nf = 0; nf < 4; ++nf)                 \
            S[e * 4 + nf] =                                              \
                (n0 + nf * 16 + fr < N) ? p[nf * 16] : 0.f;              \
        p += N;                                                          \
      }                                                                  \
    }                                                                    \
  }

#define BODY(it, CA, NA, CB)                                             \
  {                                                                      \
    bf16x8 bfr[4];                                                       \
    _Pragma("unroll") for (int e = 0; e < 8; ++e)                        \
        _Pragma("unroll") for (int nf = 0; nf < 4; ++nf)                 \
            bfr[nf][e] = (__bf16)CB[e * 4 + nf];                         \
    LOAD_B(CB, (it) + 2);                                                \
    LOAD_A(NA, (it) + 1);                                                \
    _Pragma("unroll") for (int nf = 0; nf < 4; ++nf)                     \
        _Pragma("unroll") for (int mf = 0; mf < 8; ++mf)                 \
            acc[mf][nf] = __builtin_amdgcn_mfma_f32_16x16x32_bf16(       \
                CA[mf], bfr[nf], acc[mf][nf], 0, 0, 0);                  \
  }

  LOAD_A(afA, 0);
  LOAD_B(bA, 0);
  LOAD_B(bB, 1);
  for (int it = 0; it < niters; it += 2) {
    BODY(it, afA, afB, bA);
    BODY(it + 1, afB, afA, bB);
  }
#undef BODY
#undef LOAD_B
#undef LOAD_A

  const int r0 = ks * 4;
  OutT* pbase = part + (size_t)z * 512 * npad;
#pragma unroll
  for (int mf = 0; mf < 8; ++mf)
#pragma unroll
    for (int nf = 0; nf < 4; ++nf) {
      const int col = n0 + nf * 16 + fr;
#pragma unroll
      for (int r = 0; r < 4; ++r) {
        const int row = m0 + mf * 16 + r0 + r;
        pbase[(size_t)row * npad + col] = (OutT)acc[mf][nf][r];
      }
    }
}

// sum bf16 split-K partials + bias, relu -> bf16 activations [512][4096]
__global__ __launch_bounds__(256) void reduce_relu_kernel(
    const __bf16* __restrict__ part, const float* __restrict__ bias,
    __bf16* __restrict__ out, int nsplit) {
  const int idx = blockIdx.x * 256 + threadIdx.x;
  const int flat = idx * 8;
  if (flat >= 512 * 4096) return;
  float s[8];
#pragma unroll
  for (int j = 0; j < 8; ++j) s[j] = 0.f;
  for (int sp = 0; sp < nsplit; ++sp) {
    bf16x8 v = *(const bf16x8*)(part + (size_t)sp * (512 * 4096) + flat);
#pragma unroll
    for (int j = 0; j < 8; ++j) s[j] += (float)v[j];
  }
  const int nb = flat & 4095;
  bf16x8 o;
#pragma unroll
  for (int j = 0; j < 8; ++j) {
    float v = s[j] + bias[nb + j];
    o[j] = (__bf16)(v > 0.f ? v : 0.f);
  }
  *(bf16x8*)(out + flat) = o;
}

// final: sum split-K fp32 partials (stride 128) + bias -> d_out fp32
__global__ __launch_bounds__(256) void reduce_out_kernel(
    const float* __restrict__ pc, const float* __restrict__ pr,
    const float* __restrict__ bcls, const float* __restrict__ breg,
    float* __restrict__ out, int nsplit) {
  const int gid = blockIdx.x * 256 + threadIdx.x;
  if (gid >= 512 * 105) return;
  if (gid < 512 * 21) {
    const int m = gid / 21, j = gid - m * 21;
    float s = bcls[j];
    for (int sp = 0; sp < nsplit; ++sp)
      s += pc[(size_t)sp * 512 * 128 + m * 128 + j];
    out[gid] = s;
  } else {
    const int g = gid - 512 * 21;
    const int m = g / 84, j = g - m * 84;
    float s = breg[j];
    for (int sp = 0; sp < nsplit; ++sp)
      s += pr[(size_t)sp * 512 * 128 + m * 128 + j];
    out[gid] = s;
  }
}

extern "C" void kernel_launch(void* const* d_in, const int* in_sizes, int n_in,
                              void* d_out, int out_size, void* d_ws, size_t ws_size,
                              hipStream_t stream) {
  (void)in_sizes; (void)n_in; (void)out_size;
  const float* x    = (const float*)d_in[0];
  const float* rois = (const float*)d_in[2];
  const float* W1   = (const float*)d_in[3];
  const float* b1   = (const float*)d_in[4];
  const float* W2   = (const float*)d_in[5];
  const float* b2   = (const float*)d_in[6];
  const float* Wcls = (const float*)d_in[7];
  const float* bcls = (const float*)d_in[8];
  const float* Wreg = (const float*)d_in[9];
  const float* breg = (const float*)d_in[10];
  float* out = (float*)d_out;

  const size_t pooled_b = (size_t)512 * KK1 * 2;        // 25,690,112
  const size_t act_b = (size_t)512 * D1 * 2;            // 4 MiB
  const size_t need8 = pooled_b + (size_t)8 * act_b + 2 * act_b;
  const int ns = (ws_size >= need8) ? 8 : 2;            // ws ~1.6GB: ns=8
  const int zshift = (ns == 8) ? 3 : 1;

  char* ws = (char*)d_ws;
  __bf16* pooled = (__bf16*)ws;
  __bf16* part1 = (__bf16*)(ws + pooled_b);             // ns * 4MiB
  __bf16* f1 = (__bf16*)(ws + pooled_b + (size_t)ns * act_b);
  __bf16* f2 = (__bf16*)(ws + pooled_b + (size_t)ns * act_b + act_b);
  __bf16* part2 = (__bf16*)ws;                          // alias dead pooled+part1
  float* pcls = (float*)ws;                             // heads phase aliases
  float* preg = (float*)(ws + (size_t)64 * 512 * 128 * 4);  // +16.8MB

  // 1) RoIPool -> pooled bf16 [512, 25088]
  roipool_kernel<<<N_ROIS * 8, 256, 0, stream>>>(x, rois, pooled);

  // 2) GEMM1: pooled @ W1[25088,4096]; W1 read exactly once; z-pinned XCDs
  gemm_pipe<__bf16><<<32 * ns, 256, 0, stream>>>(
      pooled, W1, part1, 4096, KK1, KK1 / ns, 4096, zshift);
  reduce_relu_kernel<<<1024, 256, 0, stream>>>(part1, b1, f1, ns);

  // 3) GEMM2: f1 @ W2[4096,4096]
  gemm_pipe<__bf16><<<32 * ns, 256, 0, stream>>>(
      f1, W2, part2, 4096, 4096, 4096 / ns, 4096, zshift);
  reduce_relu_kernel<<<1024, 256, 0, stream>>>(part2, b2, f2, ns);

  // 4) heads via gemm_small (N<128-safe), split-K=64
  gemm_small<float><<<64, 256, 0, stream>>>(
      f2, Wcls, pcls, 21, 4096, 64, 128, 6);
  gemm_small<float><<<128, 256, 0, stream>>>(
      f2, Wreg, preg, 84, 4096, 64, 128, 6);
  reduce_out_kernel<<<(512 * 105 + 255) / 256, 256, 0, stream>>>(
      pcls, preg, bcls, breg, out, 64);
}